// Round 1
// baseline (733.305 us; speedup 1.0000x reference)
//
#include <hip/hip_runtime.h>
#include <hip/hip_bf16.h>

#define SQ 4096
#define HID 1024
#define INTER_DIM 4096
#define NH 16
#define DH 64

typedef __attribute__((ext_vector_type(4))) float f32x4;
typedef __attribute__((ext_vector_type(8))) short bf16x8;

__device__ __forceinline__ float bf2f(unsigned short u) {
  union { float f; unsigned int i; } v; v.i = ((unsigned int)u) << 16; return v.f;
}
__device__ __forceinline__ unsigned short f2bf(float f) {
  union { float f; unsigned int i; } v; v.f = f;
  unsigned int i = v.i;
  return (unsigned short)((i + 0x7FFFu + ((i >> 16) & 1u)) >> 16);
}

__device__ __forceinline__ void load_lds16(const void* g, void* l) {
  __builtin_amdgcn_global_load_lds(
      (const __attribute__((address_space(1))) void*)g,
      (__attribute__((address_space(3))) void*)l, 16, 0, 0);
}

// ---------------- weight conversion fp32 -> bf16 ----------------
__global__ void cvt_kernel(const float* __restrict__ src,
                           unsigned short* __restrict__ dst, int n4) {
  int i = blockIdx.x * blockDim.x + threadIdx.x;
  if (i < n4) {
    float4 v = ((const float4*)src)[i];
    ushort4 o;
    o.x = f2bf(v.x); o.y = f2bf(v.y); o.z = f2bf(v.z); o.w = f2bf(v.w);
    ((ushort4*)dst)[i] = o;
  }
}

// ---------------- mean-only layernorm -> bf16 ----------------
__global__ __launch_bounds__(256) void ln_kernel(
    const float* __restrict__ x, const float* __restrict__ w,
    const float* __restrict__ b, unsigned short* __restrict__ out) {
  const int row = blockIdx.x;
  const int t = threadIdx.x;
  const float4 v = ((const float4*)(x + (size_t)row * HID))[t];
  float s = v.x + v.y + v.z + v.w;
  #pragma unroll
  for (int off = 32; off > 0; off >>= 1) s += __shfl_xor(s, off);
  __shared__ float red[4];
  if ((t & 63) == 0) red[t >> 6] = s;
  __syncthreads();
  const float mean = (red[0] + red[1] + red[2] + red[3]) * (1.0f / HID);
  const float4 wv = ((const float4*)w)[t];
  const float4 bv = ((const float4*)b)[t];
  ushort4 o;
  o.x = f2bf(wv.x * (v.x - mean) + bv.x);
  o.y = f2bf(wv.y * (v.y - mean) + bv.y);
  o.z = f2bf(wv.z * (v.z - mean) + bv.z);
  o.w = f2bf(wv.w * (v.w - mean) + bv.w);
  ((ushort4*)(out + (size_t)row * HID))[t] = o;
}

// ---------------- GEMM: C[M][N] = A[M][K] * B[N][K]^T + bias, epilogues ----
// MODE 0: bf16 out = (acc+bias)*scale
// MODE 1: bf16 out = relu(acc+bias)
// MODE 2: f32  out = acc+bias+res
template <int MODE>
__global__ __launch_bounds__(256) void gemm_bt(
    const unsigned short* __restrict__ A, const unsigned short* __restrict__ B,
    const float* __restrict__ bias, const float* __restrict__ res,
    void* __restrict__ Cout, int M, int N, int K, float scale) {
  __shared__ __align__(16) unsigned short As[128 * 32];
  __shared__ __align__(16) unsigned short Bs[128 * 32];
  const int t = threadIdx.x;
  const int lane = t & 63;
  const int wave = t >> 6;
  const int g = lane >> 4;
  const int lr = lane & 15;
  const int waveM = wave >> 1, waveN = wave & 1;
  const int rowBase = blockIdx.x * 128;
  const int colBase = blockIdx.y * 128;

  f32x4 acc[4][4];
  #pragma unroll
  for (int m = 0; m < 4; ++m)
    #pragma unroll
    for (int n = 0; n < 4; ++n) acc[m][n] = (f32x4){0.f, 0.f, 0.f, 0.f};

  // staging: 512 16B-chunks per tile; thread handles chunks t and t+256
  const int c0 = t, c1 = t + 256;
  const int r0s = c0 >> 2, s0 = (c0 & 3) ^ (r0s & 3);
  const int r1s = c1 >> 2, s1 = (c1 & 3) ^ (r1s & 3);
  const unsigned short* gA0 = A + (size_t)(rowBase + r0s) * K + s0 * 8;
  const unsigned short* gA1 = A + (size_t)(rowBase + r1s) * K + s1 * 8;
  const unsigned short* gB0 = B + (size_t)(colBase + r0s) * K + s0 * 8;
  const unsigned short* gB1 = B + (size_t)(colBase + r1s) * K + s1 * 8;
  unsigned short* lA0 = &As[wave * 512];
  unsigned short* lA1 = &As[2048 + wave * 512];
  unsigned short* lB0 = &Bs[wave * 512];
  unsigned short* lB1 = &Bs[2048 + wave * 512];

  for (int k0 = 0; k0 < K; k0 += 32) {
    load_lds16(gA0 + k0, lA0);
    load_lds16(gA1 + k0, lA1);
    load_lds16(gB0 + k0, lB0);
    load_lds16(gB1 + k0, lB1);
    __syncthreads();
    bf16x8 af[4], bfr[4];
    #pragma unroll
    for (int m = 0; m < 4; ++m) {
      int r = waveM * 64 + m * 16 + lr;
      af[m] = *(const bf16x8*)&As[r * 32 + ((g ^ (r & 3)) << 3)];
    }
    #pragma unroll
    for (int n = 0; n < 4; ++n) {
      int c = waveN * 64 + n * 16 + lr;
      bfr[n] = *(const bf16x8*)&Bs[c * 32 + ((g ^ (c & 3)) << 3)];
    }
    #pragma unroll
    for (int m = 0; m < 4; ++m)
      #pragma unroll
      for (int n = 0; n < 4; ++n)
        acc[m][n] = __builtin_amdgcn_mfma_f32_16x16x32_bf16(af[m], bfr[n],
                                                            acc[m][n], 0, 0, 0);
    __syncthreads();
  }

  const int crow0 = rowBase + waveM * 64;
  const int ccol0 = colBase + waveN * 64;
  #pragma unroll
  for (int n = 0; n < 4; ++n) {
    const int col = ccol0 + n * 16 + lr;
    const float bv = bias[col];
    #pragma unroll
    for (int m = 0; m < 4; ++m) {
      #pragma unroll
      for (int j = 0; j < 4; ++j) {
        const int row = crow0 + m * 16 + g * 4 + j;
        const float v = acc[m][n][j] + bv;
        if (MODE == 0) {
          ((unsigned short*)Cout)[(size_t)row * N + col] = f2bf(v * scale);
        } else if (MODE == 1) {
          ((unsigned short*)Cout)[(size_t)row * N + col] = f2bf(fmaxf(v, 0.f));
        } else {
          ((float*)Cout)[(size_t)row * N + col] = v + res[(size_t)row * N + col];
        }
      }
    }
  }
}

// ---------------- flash attention ----------------
// grid: (SQ/64, NH); 256 threads = 4 waves, each wave owns 16 q-rows.
__global__ __launch_bounds__(256) void attn_kernel(
    const unsigned short* __restrict__ Q,   // [SQ][HID], pre-scaled by 1/8
    const unsigned short* __restrict__ Kg,  // [SQ][HID]
    const unsigned short* __restrict__ Vg,  // [SQ][HID]
    unsigned short* __restrict__ ctx) {     // [SQ][HID]
  const int h = blockIdx.y;
  const int t = threadIdx.x;
  const int lane = t & 63;
  const int wave = t >> 6;
  const int g = lane >> 4;
  const int lr = lane & 15;

  __shared__ __align__(16) unsigned short Ks[32 * 64];     // swizzled [kv][d]
  __shared__ __align__(16) unsigned short Vs[64 * 40];     // [d][kv], pad 40
  __shared__ __align__(16) unsigned short Ps[4][16 * 40];  // per-wave [q][kv]

  const int qrow = blockIdx.x * 64 + wave * 16 + lr;
  const size_t qoff = (size_t)qrow * HID + h * DH;
  const bf16x8 qf0 = *(const bf16x8*)&Q[qoff + g * 8];
  const bf16x8 qf1 = *(const bf16x8*)&Q[qoff + 32 + g * 8];

  float mreg[4], lreg[4];
  f32x4 oacc[4];
  #pragma unroll
  for (int j = 0; j < 4; ++j) { mreg[j] = -1e30f; lreg[j] = 0.f; }
  #pragma unroll
  for (int n = 0; n < 4; ++n) oacc[n] = (f32x4){0.f, 0.f, 0.f, 0.f};

  // K staging: 256 chunks, chunk t -> row t>>3, swizzled slot
  const int krow = t >> 3;
  const int kslot = (t & 7) ^ (krow & 7);
  const unsigned short* gK = Kg + (size_t)krow * HID + h * DH + kslot * 8;
  unsigned short* lK = &Ks[wave * 512];
  // V staging (transpose into Vs): thread loads V[kv= t&31][d = (t>>5)*8 ..+8]
  const int vkv = t & 31;
  const int vds = t >> 5;
  const unsigned short* gV = Vg + (size_t)vkv * HID + h * DH + vds * 8;

  for (int kv0 = 0; kv0 < SQ; kv0 += 32) {
    load_lds16(gK + (size_t)kv0 * HID, lK);
    {
      bf16x8 vv = *(const bf16x8*)(gV + (size_t)kv0 * HID);
      #pragma unroll
      for (int j = 0; j < 8; ++j)
        Vs[(vds * 8 + j) * 40 + vkv] = (unsigned short)vv[j];
    }
    __syncthreads();

    // S = Q*K^T (two 16-col tiles)
    f32x4 st[2];
    #pragma unroll
    for (int tk = 0; tk < 2; ++tk) {
      const int kv = tk * 16 + lr;
      const int sw = (kv & 7) << 4;
      const int b0 = (kv * 128 + g * 16) ^ sw;
      const int b1 = (kv * 128 + 64 + g * 16) ^ sw;
      const bf16x8 k0v = *(const bf16x8*)&Ks[b0 >> 1];
      const bf16x8 k1v = *(const bf16x8*)&Ks[b1 >> 1];
      f32x4 sa = (f32x4){0.f, 0.f, 0.f, 0.f};
      sa = __builtin_amdgcn_mfma_f32_16x16x32_bf16(qf0, k0v, sa, 0, 0, 0);
      sa = __builtin_amdgcn_mfma_f32_16x16x32_bf16(qf1, k1v, sa, 0, 0, 0);
      st[tk] = sa;
    }

    // online softmax; D-layout row = 4g+j, col = lr
    #pragma unroll
    for (int j = 0; j < 4; ++j) {
      float mx = fmaxf(st[0][j], st[1][j]);
      mx = fmaxf(mx, __shfl_xor(mx, 1));
      mx = fmaxf(mx, __shfl_xor(mx, 2));
      mx = fmaxf(mx, __shfl_xor(mx, 4));
      mx = fmaxf(mx, __shfl_xor(mx, 8));
      const float mn = fmaxf(mreg[j], mx);
      const float p0 = __expf(st[0][j] - mn);
      const float p1 = __expf(st[1][j] - mn);
      const float corr = __expf(mreg[j] - mn);
      mreg[j] = mn;
      float rs = p0 + p1;
      rs += __shfl_xor(rs, 1);
      rs += __shfl_xor(rs, 2);
      rs += __shfl_xor(rs, 4);
      rs += __shfl_xor(rs, 8);
      lreg[j] = lreg[j] * corr + rs;
      #pragma unroll
      for (int n = 0; n < 4; ++n) oacc[n][j] *= corr;
      Ps[wave][(4 * g + j) * 40 + lr] = f2bf(p0);
      Ps[wave][(4 * g + j) * 40 + 16 + lr] = f2bf(p1);
    }
    __builtin_amdgcn_wave_barrier();

    // PV: A-frag of P from per-wave LDS, B-frag of V from transposed Vs
    const bf16x8 pa = *(const bf16x8*)&Ps[wave][lr * 40 + g * 8];
    #pragma unroll
    for (int n = 0; n < 4; ++n) {
      const bf16x8 vb = *(const bf16x8*)&Vs[(n * 16 + lr) * 40 + g * 8];
      oacc[n] = __builtin_amdgcn_mfma_f32_16x16x32_bf16(pa, vb, oacc[n], 0, 0, 0);
    }
    __syncthreads();
  }

  #pragma unroll
  for (int n = 0; n < 4; ++n) {
    #pragma unroll
    for (int j = 0; j < 4; ++j) {
      const int row = blockIdx.x * 64 + wave * 16 + 4 * g + j;
      const float val = oacc[n][j] / lreg[j];
      ctx[(size_t)row * HID + h * DH + n * 16 + lr] = f2bf(val);
    }
  }
}

extern "C" void kernel_launch(void* const* d_in, const int* in_sizes, int n_in,
                              void* d_out, int out_size, void* d_ws,
                              size_t ws_size, hipStream_t stream) {
  const float* x     = (const float*)d_in[0];
  const float* an_w  = (const float*)d_in[1];
  const float* an_b  = (const float*)d_in[2];
  const float* q_w   = (const float*)d_in[3];
  const float* q_b   = (const float*)d_in[4];
  const float* k_w   = (const float*)d_in[5];
  const float* k_b   = (const float*)d_in[6];
  const float* v_w   = (const float*)d_in[7];
  const float* v_b   = (const float*)d_in[8];
  const float* o_w   = (const float*)d_in[9];
  const float* o_b   = (const float*)d_in[10];
  const float* fn_w  = (const float*)d_in[11];
  const float* fn_b  = (const float*)d_in[12];
  const float* ff1_w = (const float*)d_in[13];
  const float* ff1_b = (const float*)d_in[14];
  const float* ff2_w = (const float*)d_in[15];
  const float* ff2_b = (const float*)d_in[16];

  char* ws = (char*)d_ws;
  const size_t MB = 1ull << 20;
  unsigned short* xn   = (unsigned short*)(ws + 0);       // 8MB, reused as x2n
  unsigned short* qwb  = (unsigned short*)(ws + 8 * MB);  // 2MB
  unsigned short* kwb  = (unsigned short*)(ws + 10 * MB);
  unsigned short* vwb  = (unsigned short*)(ws + 12 * MB);
  unsigned short* owb  = (unsigned short*)(ws + 14 * MB);
  unsigned short* f1wb = (unsigned short*)(ws + 16 * MB); // 8MB
  unsigned short* f2wb = (unsigned short*)(ws + 24 * MB); // 8MB
  unsigned short* Qm   = (unsigned short*)(ws + 32 * MB); // 8MB
  unsigned short* Km   = (unsigned short*)(ws + 40 * MB); // 8MB
  unsigned short* Vm   = (unsigned short*)(ws + 48 * MB); // 8MB
  unsigned short* ctx  = (unsigned short*)(ws + 56 * MB); // 8MB
  float*          x2   = (float*)(ws + 64 * MB);          // 16MB
  unsigned short* hbuf = (unsigned short*)(ws + 32 * MB); // 32MB reuse Q/K/V/ctx
  unsigned short* x2n  = xn;

  // weight conversions
  cvt_kernel<<<1024, 256, 0, stream>>>(q_w, qwb, (HID * HID) / 4);
  cvt_kernel<<<1024, 256, 0, stream>>>(k_w, kwb, (HID * HID) / 4);
  cvt_kernel<<<1024, 256, 0, stream>>>(v_w, vwb, (HID * HID) / 4);
  cvt_kernel<<<1024, 256, 0, stream>>>(o_w, owb, (HID * HID) / 4);
  cvt_kernel<<<4096, 256, 0, stream>>>(ff1_w, f1wb, (INTER_DIM * HID) / 4);
  cvt_kernel<<<4096, 256, 0, stream>>>(ff2_w, f2wb, (HID * INTER_DIM) / 4);

  // LN1
  ln_kernel<<<SQ, 256, 0, stream>>>(x, an_w, an_b, xn);

  // QKV projections (Q gets 1/sqrt(64) folded in)
  dim3 g1(SQ / 128, HID / 128);
  gemm_bt<0><<<g1, 256, 0, stream>>>(xn, qwb, q_b, nullptr, Qm, SQ, HID, HID, 0.125f);
  gemm_bt<0><<<g1, 256, 0, stream>>>(xn, kwb, k_b, nullptr, Km, SQ, HID, HID, 1.0f);
  gemm_bt<0><<<g1, 256, 0, stream>>>(xn, vwb, v_b, nullptr, Vm, SQ, HID, HID, 1.0f);

  // attention
  attn_kernel<<<dim3(SQ / 64, NH), 256, 0, stream>>>(Qm, Km, Vm, ctx);

  // O projection + residual -> x2 (fp32)
  gemm_bt<2><<<g1, 256, 0, stream>>>(ctx, owb, o_b, x, x2, SQ, HID, HID, 1.0f);

  // LN2
  ln_kernel<<<SQ, 256, 0, stream>>>(x2, fn_w, fn_b, x2n);

  // FF1 + relu -> h (bf16)
  dim3 g2(SQ / 128, INTER_DIM / 128);
  gemm_bt<1><<<g2, 256, 0, stream>>>(x2n, f1wb, ff1_b, nullptr, hbuf, SQ, INTER_DIM, HID, 1.0f);

  // FF2 + residual -> out (fp32)
  gemm_bt<2><<<g1, 256, 0, stream>>>(hbuf, f2wb, ff2_b, x2, (float*)d_out, SQ, HID, INTER_DIM, 1.0f);
}

// Round 3
// 504.715 us; speedup vs baseline: 1.4529x; 1.4529x over previous
//
#include <hip/hip_runtime.h>
#include <hip/hip_bf16.h>

#define SQ 4096
#define HID 1024
#define INTER_DIM 4096
#define NH 16
#define DH 64

typedef __attribute__((ext_vector_type(4))) float f32x4;
typedef __attribute__((ext_vector_type(16))) float f32x16;
typedef __attribute__((ext_vector_type(8))) short bf16x8;

__device__ __forceinline__ unsigned short f2bf(float f) {
  union { float f; unsigned int i; } v; v.f = f;
  unsigned int i = v.i;
  return (unsigned short)((i + 0x7FFFu + ((i >> 16) & 1u)) >> 16);
}

__device__ __forceinline__ void load_lds16(const void* g, void* l) {
  __builtin_amdgcn_global_load_lds(
      (const __attribute__((address_space(1))) void*)g,
      (__attribute__((address_space(3))) void*)l, 16, 0, 0);
}

__device__ __forceinline__ int cvtpk_bf16(float a, float b) {
  int r;
  asm("v_cvt_pk_bf16_f32 %0, %1, %2" : "=v"(r) : "v"(a), "v"(b));
  return r;
}

// ---------------- fused weight conversion fp32 -> bf16 ----------------
// dst regions (ushort4 units): q:0 k:256K v:512K o:768K ff1:1M ff2:2M
__global__ __launch_bounds__(256) void cvt6_kernel(
    const float* __restrict__ s0, const float* __restrict__ s1,
    const float* __restrict__ s2, const float* __restrict__ s3,
    const float* __restrict__ s4, const float* __restrict__ s5,
    unsigned short* __restrict__ dst) {
  const int b = blockIdx.x;
  const float* src;
  int lb;
  size_t base4;
  if (b < 4096) {
    const int r = b >> 10;
    lb = b & 1023;
    src = (r == 0) ? s0 : (r == 1) ? s1 : (r == 2) ? s2 : s3;
    base4 = (size_t)r << 18;
  } else if (b < 8192) {
    lb = b - 4096; src = s4; base4 = 1u << 20;
  } else {
    lb = b - 8192; src = s5; base4 = 2u << 20;
  }
  const int i = lb * 256 + threadIdx.x;
  const float4 v4 = ((const float4*)src)[i];
  ushort4 o4;
  o4.x = f2bf(v4.x); o4.y = f2bf(v4.y); o4.z = f2bf(v4.z); o4.w = f2bf(v4.w);
  ((ushort4*)dst)[base4 + i] = o4;
}

// ---------------- mean-only layernorm -> bf16 ----------------
__global__ __launch_bounds__(256) void ln_kernel(
    const float* __restrict__ x, const float* __restrict__ w,
    const float* __restrict__ b, unsigned short* __restrict__ out) {
  const int row = blockIdx.x;
  const int t = threadIdx.x;
  const float4 v = ((const float4*)(x + (size_t)row * HID))[t];
  float s = v.x + v.y + v.z + v.w;
  #pragma unroll
  for (int off = 32; off > 0; off >>= 1) s += __shfl_xor(s, off);
  __shared__ float red[4];
  if ((t & 63) == 0) red[t >> 6] = s;
  __syncthreads();
  const float mean = (red[0] + red[1] + red[2] + red[3]) * (1.0f / HID);
  const float4 wv = ((const float4*)w)[t];
  const float4 bv = ((const float4*)b)[t];
  ushort4 o;
  o.x = f2bf(wv.x * (v.x - mean) + bv.x);
  o.y = f2bf(wv.y * (v.y - mean) + bv.y);
  o.z = f2bf(wv.z * (v.z - mean) + bv.z);
  o.w = f2bf(wv.w * (v.w - mean) + bv.w);
  ((ushort4*)(out + (size_t)row * HID))[t] = o;
}

// ---------------- GEMM: C[M][N] = A[M][K] * B[N][K]^T + bias ----
// MODE 0: bf16 out = (acc+bias)*scale
// MODE 1: bf16 out = relu(acc+bias)
// MODE 2: f32  out = acc+bias+res
// MODE 3: bf16 out TRANSPOSED: Cout[col*M + row] = acc+bias
template <int MODE>
__global__ __launch_bounds__(256) void gemm_bt(
    const unsigned short* __restrict__ A, const unsigned short* __restrict__ B,
    const float* __restrict__ bias, const float* __restrict__ res,
    void* __restrict__ Cout, int M, int N, int K, float scale) {
  __shared__ __align__(16) unsigned short As[128 * 32];
  __shared__ __align__(16) unsigned short Bs[128 * 32];
  const int t = threadIdx.x;
  const int lane = t & 63;
  const int wave = t >> 6;
  const int g = lane >> 4;
  const int lr = lane & 15;
  const int waveM = wave >> 1, waveN = wave & 1;
  const int rowBase = blockIdx.x * 128;
  const int colBase = blockIdx.y * 128;

  f32x4 acc[4][4];
  #pragma unroll
  for (int m = 0; m < 4; ++m)
    #pragma unroll
    for (int n = 0; n < 4; ++n) acc[m][n] = (f32x4){0.f, 0.f, 0.f, 0.f};

  const int c0 = t, c1 = t + 256;
  const int r0s = c0 >> 2, s0 = (c0 & 3) ^ (r0s & 3);
  const int r1s = c1 >> 2, s1 = (c1 & 3) ^ (r1s & 3);
  const unsigned short* gA0 = A + (size_t)(rowBase + r0s) * K + s0 * 8;
  const unsigned short* gA1 = A + (size_t)(rowBase + r1s) * K + s1 * 8;
  const unsigned short* gB0 = B + (size_t)(colBase + r0s) * K + s0 * 8;
  const unsigned short* gB1 = B + (size_t)(colBase + r1s) * K + s1 * 8;
  unsigned short* lA0 = &As[wave * 512];
  unsigned short* lA1 = &As[2048 + wave * 512];
  unsigned short* lB0 = &Bs[wave * 512];
  unsigned short* lB1 = &Bs[2048 + wave * 512];

  for (int k0 = 0; k0 < K; k0 += 32) {
    load_lds16(gA0 + k0, lA0);
    load_lds16(gA1 + k0, lA1);
    load_lds16(gB0 + k0, lB0);
    load_lds16(gB1 + k0, lB1);
    __syncthreads();
    bf16x8 af[4], bfr[4];
    #pragma unroll
    for (int m = 0; m < 4; ++m) {
      int r = waveM * 64 + m * 16 + lr;
      af[m] = *(const bf16x8*)&As[r * 32 + ((g ^ (r & 3)) << 3)];
    }
    #pragma unroll
    for (int n = 0; n < 4; ++n) {
      int c = waveN * 64 + n * 16 + lr;
      bfr[n] = *(const bf16x8*)&Bs[c * 32 + ((g ^ (c & 3)) << 3)];
    }
    #pragma unroll
    for (int m = 0; m < 4; ++m)
      #pragma unroll
      for (int n = 0; n < 4; ++n)
        acc[m][n] = __builtin_amdgcn_mfma_f32_16x16x32_bf16(af[m], bfr[n],
                                                            acc[m][n], 0, 0, 0);
    __syncthreads();
  }

  const int crow0 = rowBase + waveM * 64;
  const int ccol0 = colBase + waveN * 64;
  #pragma unroll
  for (int n = 0; n < 4; ++n) {
    const int col = ccol0 + n * 16 + lr;
    const float bv = bias[col];
    #pragma unroll
    for (int m = 0; m < 4; ++m) {
      if (MODE == 3) {
        const int row0 = crow0 + m * 16 + g * 4;
        ushort4 o4;
        o4.x = f2bf(acc[m][n][0] + bv);
        o4.y = f2bf(acc[m][n][1] + bv);
        o4.z = f2bf(acc[m][n][2] + bv);
        o4.w = f2bf(acc[m][n][3] + bv);
        *(ushort4*)&((unsigned short*)Cout)[(size_t)col * M + row0] = o4;
      } else {
        #pragma unroll
        for (int j = 0; j < 4; ++j) {
          const int row = crow0 + m * 16 + g * 4 + j;
          const float v = acc[m][n][j] + bv;
          if (MODE == 0) {
            ((unsigned short*)Cout)[(size_t)row * N + col] = f2bf(v * scale);
          } else if (MODE == 1) {
            ((unsigned short*)Cout)[(size_t)row * N + col] = f2bf(fmaxf(v, 0.f));
          } else {
            ((float*)Cout)[(size_t)row * N + col] =
                v + res[(size_t)row * N + col];
          }
        }
      }
    }
  }
}

// ---------------- flash attention, swapped-QK 32x32 structure ----------------
// grid: 512 blocks (xcd-swizzled over (head, qtile)); 256 threads = 4 waves,
// each wave owns 32 q-rows. KVBLK=64, double-buffered K/V LDS.
__global__ __launch_bounds__(256, 2) void attn_kernel(
    const unsigned short* __restrict__ Q,   // [SQ][HID], prescaled 0.125*log2e
    const unsigned short* __restrict__ Kg,  // [SQ][HID]
    const unsigned short* __restrict__ Vt,  // [HID][SQ]  (per-head transposed)
    unsigned short* __restrict__ ctx) {     // [SQ][HID]
  // XCD swizzle: 2 heads per XCD
  const int s = blockIdx.y * gridDim.x + blockIdx.x;  // 0..511
  const int q6 = s >> 3;                              // 0..63
  const int h = (s & 7) * 2 + (q6 >> 5);
  const int qt = q6 & 31;

  const int t = threadIdx.x;
  const int lane = t & 63;
  const int wave = t >> 6;
  const int ql = lane & 31;
  const int hi = lane >> 5;

  __shared__ __align__(16) unsigned short Ks[2][64 * 64];
  __shared__ __align__(16) unsigned short Vs[2][64 * 64];

  // Q fragments: lane holds Q[q = qbase+ql][d = ks*16 + hi*8 + 0..7]
  const int qbase = qt * 128 + wave * 32;
  const unsigned short* qptr = Q + (size_t)(qbase + ql) * HID + h * DH + hi * 8;
  bf16x8 qf[4];
  #pragma unroll
  for (int ks = 0; ks < 4; ++ks) qf[ks] = *(const bf16x8*)(qptr + ks * 16);

  // staging source pointers (pre-swizzled global, linear LDS dest)
  const int cr = t >> 3, cs = t & 7;
  const int cr2 = cr + 32;
  const unsigned short* gK0 = Kg + (size_t)cr * HID + h * DH + ((cs ^ (cr & 7)) << 3);
  const unsigned short* gK1 = Kg + (size_t)cr2 * HID + h * DH + ((cs ^ (cr2 & 7)) << 3);
  const unsigned short* gV0 = Vt + (size_t)(h * DH + cr) * SQ + ((cs ^ (cr & 7)) << 3);
  const unsigned short* gV1 = Vt + (size_t)(h * DH + cr2) * SQ + ((cs ^ (cr2 & 7)) << 3);

  float mreg = -1e30f, lreg = 0.f;
  f32x16 oacc0 = 0.f, oacc1 = 0.f;

  // prologue: stage tile 0 into buf 0
  load_lds16(gK0, &Ks[0][wave * 512]);
  load_lds16(gK1, &Ks[0][2048 + wave * 512]);
  load_lds16(gV0, &Vs[0][wave * 512]);
  load_lds16(gV1, &Vs[0][2048 + wave * 512]);

  for (int kt = 0; kt < SQ / 64; ++kt) {
    const int buf = kt & 1;
    __syncthreads();  // staged buf ready (vmcnt drain), prev compute done
    if (kt + 1 < SQ / 64) {
      const size_t ko = (size_t)(kt + 1) * 64 * HID;
      const int vo = (kt + 1) * 64;
      load_lds16(gK0 + ko, &Ks[buf ^ 1][wave * 512]);
      load_lds16(gK1 + ko, &Ks[buf ^ 1][2048 + wave * 512]);
      load_lds16(gV0 + vo, &Vs[buf ^ 1][wave * 512]);
      load_lds16(gV1 + vo, &Vs[buf ^ 1][2048 + wave * 512]);
    }
    const unsigned short* KsB = &Ks[buf][0];
    const unsigned short* VsB = &Vs[buf][0];

    // K frags + swapped QK^T: st = S^T tiles (rows kv, cols q)
    f32x16 st0 = 0.f, st1 = 0.f;
    #pragma unroll
    for (int ks = 0; ks < 4; ++ks) {
      const int sl = ((((ks << 1) | hi) ^ (ql & 7)) << 3);
      const bf16x8 k0 = *(const bf16x8*)&KsB[ql * 64 + sl];
      const bf16x8 k1 = *(const bf16x8*)&KsB[(32 + ql) * 64 + sl];
      st0 = __builtin_amdgcn_mfma_f32_32x32x16_bf16(k0, qf[ks], st0, 0, 0, 0);
      st1 = __builtin_amdgcn_mfma_f32_32x32x16_bf16(k1, qf[ks], st1, 0, 0, 0);
    }

    // V frags (issue early; consumed after softmax)
    bf16x8 vf0[4], vf1[4];
    #pragma unroll
    for (int ks = 0; ks < 4; ++ks) {
      const int sl = ((((ks << 1) | hi) ^ (ql & 7)) << 3);
      vf0[ks] = *(const bf16x8*)&VsB[ql * 64 + sl];
      vf1[ks] = *(const bf16x8*)&VsB[(32 + ql) * 64 + sl];
    }

    // ---- online softmax, log2 domain; lane owns q=ql (32 kv per half) ----
    float mx = st0[0];
    #pragma unroll
    for (int r = 1; r < 16; ++r) mx = fmaxf(mx, st0[r]);
    #pragma unroll
    for (int r = 0; r < 16; ++r) mx = fmaxf(mx, st1[r]);
    mx = fmaxf(mx, __shfl_xor(mx, 32));

    if (!__all(mx <= mreg + 11.0f)) {   // defer-max rescale (T13)
      const float mn = fmaxf(mreg, mx);
      const float corr = exp2f(mreg - mn);
      mreg = mn;
      lreg *= corr;
      #pragma unroll
      for (int r = 0; r < 16; ++r) {
        const float c = __shfl(corr, (r & 3) + 8 * (r >> 2) + 4 * hi);
        oacc0[r] *= c;
        oacc1[r] *= c;
      }
    }

    float sum = 0.f;
    #pragma unroll
    for (int r = 0; r < 16; ++r) { st0[r] = exp2f(st0[r] - mreg); sum += st0[r]; }
    #pragma unroll
    for (int r = 0; r < 16; ++r) { st1[r] = exp2f(st1[r] - mreg); sum += st1[r]; }
    sum += __shfl_xor(sum, 32);
    lreg += sum;

    // ---- P -> A-frag via cvt_pk + permlane32_swap (T12) ----
    union { int w[4]; bf16x8 v; } pa[4];
    #pragma unroll
    for (int half = 0; half < 2; ++half) {
      // half 0: st0 (kv 0-31, ks 0/1); half 1: st1 (kv 32-63, ks 2/3)
      #pragma unroll
      for (int kk = 0; kk < 2; ++kk) {
        const int base = kk * 8;
        float p0, p1, p2, p3, p4, p5, p6, p7;
        if (half == 0) {
          p0 = st0[base + 0]; p1 = st0[base + 1]; p2 = st0[base + 2]; p3 = st0[base + 3];
          p4 = st0[base + 4]; p5 = st0[base + 5]; p6 = st0[base + 6]; p7 = st0[base + 7];
        } else {
          p0 = st1[base + 0]; p1 = st1[base + 1]; p2 = st1[base + 2]; p3 = st1[base + 3];
          p4 = st1[base + 4]; p5 = st1[base + 5]; p6 = st1[base + 6]; p7 = st1[base + 7];
        }
        const int d0 = cvtpk_bf16(p0, p1), s0 = cvtpk_bf16(p4, p5);
        const int d1 = cvtpk_bf16(p2, p3), s1 = cvtpk_bf16(p6, p7);
        auto a = __builtin_amdgcn_permlane32_swap(d0, s0, false, false);
        auto b = __builtin_amdgcn_permlane32_swap(d1, s1, false, false);
        const int ks = half * 2 + kk;
        pa[ks].w[0] = a[0]; pa[ks].w[1] = b[0];
        pa[ks].w[2] = a[1]; pa[ks].w[3] = b[1];
      }
    }

    // ---- PV ----
    #pragma unroll
    for (int ks = 0; ks < 4; ++ks) {
      oacc0 = __builtin_amdgcn_mfma_f32_32x32x16_bf16(pa[ks].v, vf0[ks], oacc0, 0, 0, 0);
      oacc1 = __builtin_amdgcn_mfma_f32_32x32x16_bf16(pa[ks].v, vf1[ks], oacc1, 0, 0, 0);
    }
  }

  // ---- epilogue: divide by l, write ctx ----
  const float linv = 1.0f / lreg;
  #pragma unroll
  for (int r = 0; r < 16; ++r) {
    const int qq = (r & 3) + 8 * (r >> 2) + 4 * hi;
    const float li = __shfl(linv, qq);
    unsigned short* cp = ctx + (size_t)(qbase + qq) * HID + h * DH + ql;
    cp[0] = f2bf(oacc0[r] * li);
    cp[32] = f2bf(oacc1[r] * li);
  }
}

extern "C" void kernel_launch(void* const* d_in, const int* in_sizes, int n_in,
                              void* d_out, int out_size, void* d_ws,
                              size_t ws_size, hipStream_t stream) {
  const float* x     = (const float*)d_in[0];
  const float* an_w  = (const float*)d_in[1];
  const float* an_b  = (const float*)d_in[2];
  const float* q_w   = (const float*)d_in[3];
  const float* q_b   = (const float*)d_in[4];
  const float* k_w   = (const float*)d_in[5];
  const float* k_b   = (const float*)d_in[6];
  const float* v_w   = (const float*)d_in[7];
  const float* v_b   = (const float*)d_in[8];
  const float* o_w   = (const float*)d_in[9];
  const float* o_b   = (const float*)d_in[10];
  const float* fn_w  = (const float*)d_in[11];
  const float* fn_b  = (const float*)d_in[12];
  const float* ff1_w = (const float*)d_in[13];
  const float* ff1_b = (const float*)d_in[14];
  const float* ff2_w = (const float*)d_in[15];
  const float* ff2_b = (const float*)d_in[16];

  char* ws = (char*)d_ws;
  const size_t MB = 1ull << 20;
  unsigned short* xn   = (unsigned short*)(ws + 0);       // 8MB, reused as x2n
  unsigned short* qwb  = (unsigned short*)(ws + 8 * MB);  // 2MB (cvt6 regions)
  unsigned short* kwb  = (unsigned short*)(ws + 10 * MB);
  unsigned short* vwb  = (unsigned short*)(ws + 12 * MB);
  unsigned short* owb  = (unsigned short*)(ws + 14 * MB);
  unsigned short* f1wb = (unsigned short*)(ws + 16 * MB); // 8MB
  unsigned short* f2wb = (unsigned short*)(ws + 24 * MB); // 8MB
  unsigned short* Qm   = (unsigned short*)(ws + 32 * MB); // 8MB
  unsigned short* Km   = (unsigned short*)(ws + 40 * MB); // 8MB
  unsigned short* Vtm  = (unsigned short*)(ws + 48 * MB); // 8MB [HID][SQ]
  unsigned short* ctx  = (unsigned short*)(ws + 56 * MB); // 8MB
  float*          x2   = (float*)(ws + 64 * MB);          // 16MB
  unsigned short* hbuf = (unsigned short*)(ws + 32 * MB); // 32MB reuse Q/K/V/ctx
  unsigned short* x2n  = xn;

  // fused weight conversion (regions contiguous from ws+8MB)
  cvt6_kernel<<<12288, 256, 0, stream>>>(q_w, k_w, v_w, o_w, ff1_w, ff2_w, qwb);

  // LN1
  ln_kernel<<<SQ, 256, 0, stream>>>(x, an_w, an_b, xn);

  // QKV projections. Q folds 1/sqrt(64) * log2(e) for exp2-domain softmax.
  dim3 g1(SQ / 128, HID / 128);
  gemm_bt<0><<<g1, 256, 0, stream>>>(xn, qwb, q_b, nullptr, Qm, SQ, HID, HID,
                                     0.125f * 1.44269504f);
  gemm_bt<0><<<g1, 256, 0, stream>>>(xn, kwb, k_b, nullptr, Km, SQ, HID, HID, 1.0f);
  gemm_bt<3><<<g1, 256, 0, stream>>>(xn, vwb, v_b, nullptr, Vtm, SQ, HID, HID, 1.0f);

  // attention
  attn_kernel<<<dim3(32, 16), 256, 0, stream>>>(Qm, Km, Vtm, ctx);

  // O projection + residual -> x2 (fp32)
  gemm_bt<2><<<g1, 256, 0, stream>>>(ctx, owb, o_b, x, x2, SQ, HID, HID, 1.0f);

  // LN2
  ln_kernel<<<SQ, 256, 0, stream>>>(x2, fn_w, fn_b, x2n);

  // FF1 + relu -> h (bf16)
  dim3 g2(SQ / 128, INTER_DIM / 128);
  gemm_bt<1><<<g2, 256, 0, stream>>>(x2n, f1wb, ff1_b, nullptr, hbuf, SQ,
                                     INTER_DIM, HID, 1.0f);

  // FF2 + residual -> out (fp32)
  gemm_bt<2><<<g1, 256, 0, stream>>>(hbuf, f2wb, ff2_b, x2, (float*)d_out, SQ,
                                     HID, INTER_DIM, 1.0f);
}

// Round 4
// 446.700 us; speedup vs baseline: 1.6416x; 1.1299x over previous
//
#include <hip/hip_runtime.h>
#include <hip/hip_bf16.h>

#define SQ 4096
#define HID 1024
#define INTER_DIM 4096
#define NH 16
#define DH 64
#define SCALE_Q 0.18033688f  // 0.125 * log2(e), folded into q_w/q_b

typedef __attribute__((ext_vector_type(4))) float f32x4;
typedef __attribute__((ext_vector_type(16))) float f32x16;
typedef __attribute__((ext_vector_type(8))) short bf16x8;

__device__ __forceinline__ unsigned short f2bf(float f) {
  union { float f; unsigned int i; } v; v.f = f;
  unsigned int i = v.i;
  return (unsigned short)((i + 0x7FFFu + ((i >> 16) & 1u)) >> 16);
}

__device__ __forceinline__ void load_lds16(const void* g, void* l) {
  __builtin_amdgcn_global_load_lds(
      (const __attribute__((address_space(1))) void*)g,
      (__attribute__((address_space(3))) void*)l, 16, 0, 0);
}

__device__ __forceinline__ int cvtpk_bf16(float a, float b) {
  int r;
  asm("v_cvt_pk_bf16_f32 %0, %1, %2" : "=v"(r) : "v"(a), "v"(b));
  return r;
}

// ---------------- fused weight conversion fp32 -> bf16 ----------------
// dst regions (ushort4 units): q:0 k:256K v:512K o:768K ff1:1M ff2:2M
// q region scaled by SCALE_Q (folds attention scale + log2e into Q proj).
__global__ __launch_bounds__(256) void cvt6_kernel(
    const float* __restrict__ s0, const float* __restrict__ s1,
    const float* __restrict__ s2, const float* __restrict__ s3,
    const float* __restrict__ s4, const float* __restrict__ s5,
    unsigned short* __restrict__ dst) {
  const int b = blockIdx.x;
  const float* src;
  int lb;
  size_t base4;
  if (b < 4096) {
    const int r = b >> 10;
    lb = b & 1023;
    src = (r == 0) ? s0 : (r == 1) ? s1 : (r == 2) ? s2 : s3;
    base4 = (size_t)r << 18;
  } else if (b < 8192) {
    lb = b - 4096; src = s4; base4 = 1u << 20;
  } else {
    lb = b - 8192; src = s5; base4 = 2u << 20;
  }
  const float sc = (b < 1024) ? SCALE_Q : 1.0f;
  const int i = lb * 256 + threadIdx.x;
  const float4 v4 = ((const float4*)src)[i];
  ushort4 o4;
  o4.x = f2bf(v4.x * sc); o4.y = f2bf(v4.y * sc);
  o4.z = f2bf(v4.z * sc); o4.w = f2bf(v4.w * sc);
  ((ushort4*)dst)[base4 + i] = o4;
}

// ---------------- concat q/k/v biases (q scaled) ----------------
__global__ __launch_bounds__(256) void bias3_kernel(
    const float* __restrict__ qb, const float* __restrict__ kb,
    const float* __restrict__ vb, float* __restrict__ dst) {
  const int b = blockIdx.x, t = threadIdx.x;
  const float* s = (b == 0) ? qb : (b == 1) ? kb : vb;
  float4 v = ((const float4*)s)[t];
  if (b == 0) { v.x *= SCALE_Q; v.y *= SCALE_Q; v.z *= SCALE_Q; v.w *= SCALE_Q; }
  ((float4*)dst)[b * 256 + t] = v;
}

// ---------------- mean-only layernorm -> bf16 ----------------
__global__ __launch_bounds__(256) void ln_kernel(
    const float* __restrict__ x, const float* __restrict__ w,
    const float* __restrict__ b, unsigned short* __restrict__ out) {
  const int row = blockIdx.x;
  const int t = threadIdx.x;
  const float4 v = ((const float4*)(x + (size_t)row * HID))[t];
  float s = v.x + v.y + v.z + v.w;
  #pragma unroll
  for (int off = 32; off > 0; off >>= 1) s += __shfl_xor(s, off);
  __shared__ float red[4];
  if ((t & 63) == 0) red[t >> 6] = s;
  __syncthreads();
  const float mean = (red[0] + red[1] + red[2] + red[3]) * (1.0f / HID);
  const float4 wv = ((const float4*)w)[t];
  const float4 bv = ((const float4*)b)[t];
  ushort4 o;
  o.x = f2bf(wv.x * (v.x - mean) + bv.x);
  o.y = f2bf(wv.y * (v.y - mean) + bv.y);
  o.z = f2bf(wv.z * (v.z - mean) + bv.z);
  o.w = f2bf(wv.w * (v.w - mean) + bv.w);
  ((ushort4*)(out + (size_t)row * HID))[t] = o;
}

// ---------------- GEMM: C[M][N] = A[M][K] * B[N][K]^T + bias ----
// Double-buffered LDS, prefetch-before-compute (T3-lite 2-phase).
// MODE 1: bf16 out = relu(acc+bias)
// MODE 2: f32  out = acc+bias+res
// MODE 4: fused QKV epilogue: cols<2048 -> bf16 Cout[row*2048+col];
//         cols>=2048 -> bf16 transposed Cout2[(col-2048)*M + row]
template <int MODE>
__global__ __launch_bounds__(256) void gemm_bt(
    const unsigned short* __restrict__ A, const unsigned short* __restrict__ B,
    const float* __restrict__ bias, const float* __restrict__ res,
    void* __restrict__ Cout, void* __restrict__ Cout2, int M, int N, int K) {
  __shared__ __align__(16) unsigned short As[2][128 * 32];
  __shared__ __align__(16) unsigned short Bs[2][128 * 32];
  const int t = threadIdx.x;
  const int lane = t & 63;
  const int wave = t >> 6;
  const int g = lane >> 4;
  const int lr = lane & 15;
  const int waveM = wave >> 1, waveN = wave & 1;
  const int rowBase = blockIdx.x * 128;
  const int colBase = blockIdx.y * 128;

  f32x4 acc[4][4];
  #pragma unroll
  for (int m = 0; m < 4; ++m)
    #pragma unroll
    for (int n = 0; n < 4; ++n) acc[m][n] = (f32x4){0.f, 0.f, 0.f, 0.f};

  const int c0 = t, c1 = t + 256;
  const int r0s = c0 >> 2, s0 = (c0 & 3) ^ (r0s & 3);
  const int r1s = c1 >> 2, s1 = (c1 & 3) ^ (r1s & 3);
  const unsigned short* gA0 = A + (size_t)(rowBase + r0s) * K + s0 * 8;
  const unsigned short* gA1 = A + (size_t)(rowBase + r1s) * K + s1 * 8;
  const unsigned short* gB0 = B + (size_t)(colBase + r0s) * K + s0 * 8;
  const unsigned short* gB1 = B + (size_t)(colBase + r1s) * K + s1 * 8;

  // prologue: stage tile 0 into buf 0
  load_lds16(gA0, &As[0][wave * 512]);
  load_lds16(gA1, &As[0][2048 + wave * 512]);
  load_lds16(gB0, &Bs[0][wave * 512]);
  load_lds16(gB1, &Bs[0][2048 + wave * 512]);
  __syncthreads();

  const int nk = K >> 5;
  for (int kt = 0; kt < nk; ++kt) {
    const int buf = kt & 1;
    if (kt + 1 < nk) {  // prefetch next tile into other buffer
      const int k0 = (kt + 1) << 5;
      load_lds16(gA0 + k0, &As[buf ^ 1][wave * 512]);
      load_lds16(gA1 + k0, &As[buf ^ 1][2048 + wave * 512]);
      load_lds16(gB0 + k0, &Bs[buf ^ 1][wave * 512]);
      load_lds16(gB1 + k0, &Bs[buf ^ 1][2048 + wave * 512]);
    }
    bf16x8 af[4], bfr[4];
    #pragma unroll
    for (int m = 0; m < 4; ++m) {
      const int r = waveM * 64 + m * 16 + lr;
      af[m] = *(const bf16x8*)&As[buf][r * 32 + ((g ^ (r & 3)) << 3)];
    }
    #pragma unroll
    for (int n = 0; n < 4; ++n) {
      const int c = waveN * 64 + n * 16 + lr;
      bfr[n] = *(const bf16x8*)&Bs[buf][c * 32 + ((g ^ (c & 3)) << 3)];
    }
    #pragma unroll
    for (int m = 0; m < 4; ++m)
      #pragma unroll
      for (int n = 0; n < 4; ++n)
        acc[m][n] = __builtin_amdgcn_mfma_f32_16x16x32_bf16(af[m], bfr[n],
                                                            acc[m][n], 0, 0, 0);
    __syncthreads();  // drains vmcnt(0): prefetched buf ready; reads done
  }

  const int crow0 = rowBase + waveM * 64;
  const int ccol0 = colBase + waveN * 64;
  #pragma unroll
  for (int n = 0; n < 4; ++n) {
    const int col = ccol0 + n * 16 + lr;
    const float bv = bias[col];
    #pragma unroll
    for (int m = 0; m < 4; ++m) {
      const int row0 = crow0 + m * 16 + g * 4;
      if (MODE == 4) {
        if (col < 2048) {
          #pragma unroll
          for (int j = 0; j < 4; ++j)
            ((unsigned short*)Cout)[(size_t)(row0 + j) * 2048 + col] =
                f2bf(acc[m][n][j] + bv);
        } else {
          ushort4 o4;
          o4.x = f2bf(acc[m][n][0] + bv);
          o4.y = f2bf(acc[m][n][1] + bv);
          o4.z = f2bf(acc[m][n][2] + bv);
          o4.w = f2bf(acc[m][n][3] + bv);
          *(ushort4*)&((unsigned short*)Cout2)[(size_t)(col - 2048) * M + row0] = o4;
        }
      } else if (MODE == 1) {
        #pragma unroll
        for (int j = 0; j < 4; ++j)
          ((unsigned short*)Cout)[(size_t)(row0 + j) * N + col] =
              f2bf(fmaxf(acc[m][n][j] + bv, 0.f));
      } else {
        #pragma unroll
        for (int j = 0; j < 4; ++j)
          ((float*)Cout)[(size_t)(row0 + j) * N + col] =
              acc[m][n][j] + bv + res[(size_t)(row0 + j) * N + col];
      }
    }
  }
}

// ---------------- flash attention, swapped-QK 32x32 structure ----------------
// grid: 512 blocks (xcd-swizzled over (head, qtile)); 256 threads = 4 waves,
// each wave owns 32 q-rows. KVBLK=64, double-buffered K/V LDS.
// Softmax in log2 domain with shifted accumulator init (C = -mreg).
__global__ __launch_bounds__(256, 2) void attn_kernel(
    const unsigned short* __restrict__ QK,  // [SQ][2048]: Q cols 0-1023, K 1024-2047
    const unsigned short* __restrict__ Vt,  // [HID][SQ]  (per-head transposed)
    unsigned short* __restrict__ ctx) {     // [SQ][HID]
  const int s = blockIdx.y * gridDim.x + blockIdx.x;  // 0..511
  const int q6 = s >> 3;                              // 0..63
  const int h = (s & 7) * 2 + (q6 >> 5);
  const int qt = q6 & 31;

  const int t = threadIdx.x;
  const int lane = t & 63;
  const int wave = t >> 6;
  const int ql = lane & 31;
  const int hi = lane >> 5;

  __shared__ __align__(16) unsigned short Ks[2][64 * 64];
  __shared__ __align__(16) unsigned short Vs[2][64 * 64];

  // Q fragments: lane holds Q[q = qbase+ql][d = ks*16 + hi*8 + 0..7]
  const int qbase = qt * 128 + wave * 32;
  const unsigned short* qptr =
      QK + (size_t)(qbase + ql) * 2048 + h * DH + hi * 8;
  bf16x8 qf[4];
  #pragma unroll
  for (int ks = 0; ks < 4; ++ks) qf[ks] = *(const bf16x8*)(qptr + ks * 16);

  // staging source pointers (pre-swizzled global, linear LDS dest)
  const int cr = t >> 3, cs = t & 7;
  const int cr2 = cr + 32;
  const unsigned short* gK0 =
      QK + (size_t)cr * 2048 + 1024 + h * DH + ((cs ^ (cr & 7)) << 3);
  const unsigned short* gK1 =
      QK + (size_t)cr2 * 2048 + 1024 + h * DH + ((cs ^ (cr2 & 7)) << 3);
  const unsigned short* gV0 = Vt + (size_t)(h * DH + cr) * SQ + ((cs ^ (cr & 7)) << 3);
  const unsigned short* gV1 = Vt + (size_t)(h * DH + cr2) * SQ + ((cs ^ (cr2 & 7)) << 3);

  float mreg = 0.f, lreg = 0.f;
  f32x16 oacc0 = 0.f, oacc1 = 0.f;

  // prologue: stage tile 0 into buf 0
  load_lds16(gK0, &Ks[0][wave * 512]);
  load_lds16(gK1, &Ks[0][2048 + wave * 512]);
  load_lds16(gV0, &Vs[0][wave * 512]);
  load_lds16(gV1, &Vs[0][2048 + wave * 512]);

  for (int kt = 0; kt < SQ / 64; ++kt) {
    const int buf = kt & 1;
    __syncthreads();  // staged buf ready (vmcnt drain), prev compute done
    if (kt + 1 < SQ / 64) {
      const size_t ko = (size_t)(kt + 1) * 64 * 2048;
      const int vo = (kt + 1) * 64;
      load_lds16(gK0 + ko, &Ks[buf ^ 1][wave * 512]);
      load_lds16(gK1 + ko, &Ks[buf ^ 1][2048 + wave * 512]);
      load_lds16(gV0 + vo, &Vs[buf ^ 1][wave * 512]);
      load_lds16(gV1 + vo, &Vs[buf ^ 1][2048 + wave * 512]);
    }
    const unsigned short* KsB = &Ks[buf][0];
    const unsigned short* VsB = &Vs[buf][0];

    // swapped QK^T with shifted C-init: st = S - mreg directly
    f32x16 st0, st1;
    #pragma unroll
    for (int r = 0; r < 16; ++r) { st0[r] = -mreg; st1[r] = -mreg; }
    __builtin_amdgcn_s_setprio(1);
    #pragma unroll
    for (int ks = 0; ks < 4; ++ks) {
      const int sl = ((((ks << 1) | hi) ^ (ql & 7)) << 3);
      const bf16x8 k0 = *(const bf16x8*)&KsB[ql * 64 + sl];
      const bf16x8 k1 = *(const bf16x8*)&KsB[(32 + ql) * 64 + sl];
      st0 = __builtin_amdgcn_mfma_f32_32x32x16_bf16(k0, qf[ks], st0, 0, 0, 0);
      st1 = __builtin_amdgcn_mfma_f32_32x32x16_bf16(k1, qf[ks], st1, 0, 0, 0);
    }
    __builtin_amdgcn_s_setprio(0);

    // V frags (issue early; consumed after softmax)
    bf16x8 vf0[4], vf1[4];
    #pragma unroll
    for (int ks = 0; ks < 4; ++ks) {
      const int sl = ((((ks << 1) | hi) ^ (ql & 7)) << 3);
      vf0[ks] = *(const bf16x8*)&VsB[ql * 64 + sl];
      vf1[ks] = *(const bf16x8*)&VsB[(32 + ql) * 64 + sl];
    }

    // ---- online softmax (log2 domain, values pre-shifted by -mreg) ----
    float tr[16];
    #pragma unroll
    for (int r = 0; r < 16; ++r) tr[r] = fmaxf(st0[r], st1[r]);
    #pragma unroll
    for (int s2 = 8; s2 > 0; s2 >>= 1)
      #pragma unroll
      for (int r = 0; r < s2; ++r) tr[r] = fmaxf(tr[r], tr[r + s2]);
    const float mx = fmaxf(tr[0], __shfl_xor(tr[0], 32));

    if (!__all(mx <= 8.0f)) {  // defer-max rescale (T13)
      const float mpos = fmaxf(mx, 0.f);
      const float corr = exp2f(-mpos);
      mreg += mpos;
      lreg *= corr;
      #pragma unroll
      for (int r = 0; r < 16; ++r) { st0[r] -= mpos; st1[r] -= mpos; }
      #pragma unroll
      for (int r = 0; r < 16; ++r) {
        const float c = __shfl(corr, (r & 3) + 8 * (r >> 2) + 4 * hi);
        oacc0[r] *= c;
        oacc1[r] *= c;
      }
    }

    #pragma unroll
    for (int r = 0; r < 16; ++r) st0[r] = exp2f(st0[r]);
    #pragma unroll
    for (int r = 0; r < 16; ++r) st1[r] = exp2f(st1[r]);
    float ts[16];
    #pragma unroll
    for (int r = 0; r < 16; ++r) ts[r] = st0[r] + st1[r];
    #pragma unroll
    for (int s2 = 8; s2 > 0; s2 >>= 1)
      #pragma unroll
      for (int r = 0; r < s2; ++r) ts[r] += ts[r + s2];
    lreg += ts[0] + __shfl_xor(ts[0], 32);

    // ---- P -> A-frag via cvt_pk + permlane32_swap (T12) ----
    union { int w[4]; bf16x8 v; } pa[4];
    #pragma unroll
    for (int half = 0; half < 2; ++half) {
      #pragma unroll
      for (int kk = 0; kk < 2; ++kk) {
        const int base = kk * 8;
        float p0, p1, p2, p3, p4, p5, p6, p7;
        if (half == 0) {
          p0 = st0[base + 0]; p1 = st0[base + 1]; p2 = st0[base + 2]; p3 = st0[base + 3];
          p4 = st0[base + 4]; p5 = st0[base + 5]; p6 = st0[base + 6]; p7 = st0[base + 7];
        } else {
          p0 = st1[base + 0]; p1 = st1[base + 1]; p2 = st1[base + 2]; p3 = st1[base + 3];
          p4 = st1[base + 4]; p5 = st1[base + 5]; p6 = st1[base + 6]; p7 = st1[base + 7];
        }
        const int d0 = cvtpk_bf16(p0, p1), sw0 = cvtpk_bf16(p4, p5);
        const int d1 = cvtpk_bf16(p2, p3), sw1 = cvtpk_bf16(p6, p7);
        auto a = __builtin_amdgcn_permlane32_swap(d0, sw0, false, false);
        auto b = __builtin_amdgcn_permlane32_swap(d1, sw1, false, false);
        const int ks = half * 2 + kk;
        pa[ks].w[0] = a[0]; pa[ks].w[1] = b[0];
        pa[ks].w[2] = a[1]; pa[ks].w[3] = b[1];
      }
    }

    // ---- PV ----
    __builtin_amdgcn_s_setprio(1);
    #pragma unroll
    for (int ks = 0; ks < 4; ++ks) {
      oacc0 = __builtin_amdgcn_mfma_f32_32x32x16_bf16(pa[ks].v, vf0[ks], oacc0, 0, 0, 0);
      oacc1 = __builtin_amdgcn_mfma_f32_32x32x16_bf16(pa[ks].v, vf1[ks], oacc1, 0, 0, 0);
    }
    __builtin_amdgcn_s_setprio(0);
  }

  // ---- epilogue: divide by l, write ctx ----
  const float linv = 1.0f / lreg;
  #pragma unroll
  for (int r = 0; r < 16; ++r) {
    const int qq = (r & 3) + 8 * (r >> 2) + 4 * hi;
    const float li = __shfl(linv, qq);
    unsigned short* cp = ctx + (size_t)(qbase + qq) * HID + h * DH + ql;
    cp[0] = f2bf(oacc0[r] * li);
    cp[32] = f2bf(oacc1[r] * li);
  }
}

extern "C" void kernel_launch(void* const* d_in, const int* in_sizes, int n_in,
                              void* d_out, int out_size, void* d_ws,
                              size_t ws_size, hipStream_t stream) {
  const float* x     = (const float*)d_in[0];
  const float* an_w  = (const float*)d_in[1];
  const float* an_b  = (const float*)d_in[2];
  const float* q_w   = (const float*)d_in[3];
  const float* q_b   = (const float*)d_in[4];
  const float* k_w   = (const float*)d_in[5];
  const float* k_b   = (const float*)d_in[6];
  const float* v_w   = (const float*)d_in[7];
  const float* v_b   = (const float*)d_in[8];
  const float* o_w   = (const float*)d_in[9];
  const float* o_b   = (const float*)d_in[10];
  const float* fn_w  = (const float*)d_in[11];
  const float* fn_b  = (const float*)d_in[12];
  const float* ff1_w = (const float*)d_in[13];
  const float* ff1_b = (const float*)d_in[14];
  const float* ff2_w = (const float*)d_in[15];
  const float* ff2_b = (const float*)d_in[16];

  char* ws = (char*)d_ws;
  const size_t MB = 1ull << 20;
  unsigned short* xn    = (unsigned short*)(ws + 0);       // 8MB, reused as x2n
  unsigned short* qkvwb = (unsigned short*)(ws + 8 * MB);  // 6MB [3072][1024]
  unsigned short* owb   = (unsigned short*)(ws + 14 * MB); // 2MB
  unsigned short* f1wb  = (unsigned short*)(ws + 16 * MB); // 8MB
  unsigned short* f2wb  = (unsigned short*)(ws + 24 * MB); // 8MB
  unsigned short* QKm   = (unsigned short*)(ws + 32 * MB); // 16MB [SQ][2048]
  unsigned short* Vtm   = (unsigned short*)(ws + 48 * MB); // 8MB [1024][SQ]
  unsigned short* ctx   = (unsigned short*)(ws + 56 * MB); // 8MB
  float*          bAll  = (float*)(ws + 56 * MB);          // 12KB (dead before ctx written)
  float*          x2    = (float*)(ws + 64 * MB);          // 16MB fp32
  unsigned short* hbuf  = (unsigned short*)(ws + 32 * MB); // 32MB reuse QK/Vt/ctx
  unsigned short* x2n   = xn;

  // weight conversion (q region pre-scaled) + bias concat
  cvt6_kernel<<<12288, 256, 0, stream>>>(q_w, k_w, v_w, o_w, ff1_w, ff2_w, qkvwb);
  bias3_kernel<<<3, 256, 0, stream>>>(q_b, k_b, v_b, bAll);

  // LN1
  ln_kernel<<<SQ, 256, 0, stream>>>(x, an_w, an_b, xn);

  // fused QKV projection: N=3072, writes QKm (Q,K) + Vtm (V transposed)
  gemm_bt<4><<<dim3(SQ / 128, 3072 / 128), 256, 0, stream>>>(
      xn, qkvwb, bAll, nullptr, QKm, Vtm, SQ, 3072, HID);

  // attention
  attn_kernel<<<dim3(32, 16), 256, 0, stream>>>(QKm, Vtm, ctx);

  // O projection + residual -> x2 (fp32)
  gemm_bt<2><<<dim3(SQ / 128, HID / 128), 256, 0, stream>>>(
      ctx, owb, o_b, x, x2, nullptr, SQ, HID, HID);

  // LN2
  ln_kernel<<<SQ, 256, 0, stream>>>(x2, fn_w, fn_b, x2n);

  // FF1 + relu -> h (bf16)
  gemm_bt<1><<<dim3(SQ / 128, INTER_DIM / 128), 256, 0, stream>>>(
      x2n, f1wb, ff1_b, nullptr, hbuf, nullptr, SQ, INTER_DIM, HID);

  // FF2 + residual -> out (fp32)
  gemm_bt<2><<<dim3(SQ / 128, HID / 128), 256, 0, stream>>>(
      hbuf, f2wb, ff2_b, x2, (float*)d_out, nullptr, SQ, HID, INTER_DIM);
}

// Round 5
// 409.018 us; speedup vs baseline: 1.7928x; 1.0921x over previous
//
#include <hip/hip_runtime.h>
#include <hip/hip_bf16.h>

#define SQ 4096
#define HID 1024
#define INTER_DIM 4096
#define NH 16
#define DH 64
#define SCALE_Q 0.18033688f  // 0.125 * log2(e), folded into q_w/q_b

typedef __attribute__((ext_vector_type(4))) float f32x4;
typedef __attribute__((ext_vector_type(16))) float f32x16;
typedef __attribute__((ext_vector_type(8))) short bf16x8;

__device__ __forceinline__ unsigned short f2bf(float f) {
  union { float f; unsigned int i; } v; v.f = f;
  unsigned int i = v.i;
  return (unsigned short)((i + 0x7FFFu + ((i >> 16) & 1u)) >> 16);
}

__device__ __forceinline__ void load_lds16(const void* g, void* l) {
  __builtin_amdgcn_global_load_lds(
      (const __attribute__((address_space(1))) void*)g,
      (__attribute__((address_space(3))) void*)l, 16, 0, 0);
}

__device__ __forceinline__ int cvtpk_bf16(float a, float b) {
  int r;
  asm("v_cvt_pk_bf16_f32 %0, %1, %2" : "=v"(r) : "v"(a), "v"(b));
  return r;
}

// native 2^x (we work in log2 domain). s_nop covers the trans->VALU hazard
// the compiler can't see through inline asm.
__device__ __forceinline__ float fexp2(float x) {
  float r;
  asm("v_exp_f32 %0, %1\n\ts_nop 1" : "=v"(r) : "v"(x));
  return r;
}

// ---------------- fused weight conversion fp32 -> bf16 ----------------
// dst regions (ushort4 units): q:0 k:256K v:512K o:768K ff1:1M ff2:2M
// q region scaled by SCALE_Q (folds attention scale + log2e into Q proj).
__global__ __launch_bounds__(256) void cvt6_kernel(
    const float* __restrict__ s0, const float* __restrict__ s1,
    const float* __restrict__ s2, const float* __restrict__ s3,
    const float* __restrict__ s4, const float* __restrict__ s5,
    unsigned short* __restrict__ dst) {
  const int b = blockIdx.x;
  const float* src;
  int lb;
  size_t base4;
  if (b < 4096) {
    const int r = b >> 10;
    lb = b & 1023;
    src = (r == 0) ? s0 : (r == 1) ? s1 : (r == 2) ? s2 : s3;
    base4 = (size_t)r << 18;
  } else if (b < 8192) {
    lb = b - 4096; src = s4; base4 = 1u << 20;
  } else {
    lb = b - 8192; src = s5; base4 = 2u << 20;
  }
  const float sc = (b < 1024) ? SCALE_Q : 1.0f;
  const int i = lb * 256 + threadIdx.x;
  const float4 v4 = ((const float4*)src)[i];
  ushort4 o4;
  o4.x = f2bf(v4.x * sc); o4.y = f2bf(v4.y * sc);
  o4.z = f2bf(v4.z * sc); o4.w = f2bf(v4.w * sc);
  ((ushort4*)dst)[base4 + i] = o4;
}

// ---------------- concat q/k/v biases (q scaled) ----------------
__global__ __launch_bounds__(256) void bias3_kernel(
    const float* __restrict__ qb, const float* __restrict__ kb,
    const float* __restrict__ vb, float* __restrict__ dst) {
  const int b = blockIdx.x, t = threadIdx.x;
  const float* s = (b == 0) ? qb : (b == 1) ? kb : vb;
  float4 v = ((const float4*)s)[t];
  if (b == 0) { v.x *= SCALE_Q; v.y *= SCALE_Q; v.z *= SCALE_Q; v.w *= SCALE_Q; }
  ((float4*)dst)[b * 256 + t] = v;
}

// ---------------- mean-only layernorm -> bf16 ----------------
__global__ __launch_bounds__(256) void ln_kernel(
    const float* __restrict__ x, const float* __restrict__ w,
    const float* __restrict__ b, unsigned short* __restrict__ out) {
  const int row = blockIdx.x;
  const int t = threadIdx.x;
  const float4 v = ((const float4*)(x + (size_t)row * HID))[t];
  float s = v.x + v.y + v.z + v.w;
  #pragma unroll
  for (int off = 32; off > 0; off >>= 1) s += __shfl_xor(s, off);
  __shared__ float red[4];
  if ((t & 63) == 0) red[t >> 6] = s;
  __syncthreads();
  const float mean = (red[0] + red[1] + red[2] + red[3]) * (1.0f / HID);
  const float4 wv = ((const float4*)w)[t];
  const float4 bv = ((const float4*)b)[t];
  ushort4 o;
  o.x = f2bf(wv.x * (v.x - mean) + bv.x);
  o.y = f2bf(wv.y * (v.y - mean) + bv.y);
  o.z = f2bf(wv.z * (v.z - mean) + bv.z);
  o.w = f2bf(wv.w * (v.w - mean) + bv.w);
  ((ushort4*)(out + (size_t)row * HID))[t] = o;
}

// ---------------- final combine for split-K FF2: out += p1 + res ----------
__global__ __launch_bounds__(256) void combine_kernel(
    float* __restrict__ out, const float* __restrict__ p1,
    const float* __restrict__ res) {
  const int i = blockIdx.x * 256 + threadIdx.x;
  float4 o = ((const float4*)out)[i];
  const float4 a = ((const float4*)p1)[i];
  const float4 r = ((const float4*)res)[i];
  o.x += a.x + r.x; o.y += a.y + r.y; o.z += a.z + r.z; o.w += a.w + r.w;
  ((float4*)out)[i] = o;
}

// ---------------- GEMM: C[M][N] = A[M][K] * B[N][K]^T + bias ----
// Double-buffered LDS, prefetch-before-compute (T3-lite 2-phase).
// MODE 1: bf16 out = relu(acc+bias)
// MODE 2: f32  out = acc+bias+res
// MODE 4: fused QKV epilogue: cols<2048 -> bf16 Cout[row*2048+col];
//         cols>=2048 -> bf16 transposed Cout2[(col-2048)*M + row]
// MODE 5: split-K over blockIdx.z (2 halves): z=0 -> f32 Cout = acc+bias;
//         z=1 -> f32 Cout2 = acc
template <int MODE>
__global__ __launch_bounds__(256) void gemm_bt(
    const unsigned short* __restrict__ A, const unsigned short* __restrict__ B,
    const float* __restrict__ bias, const float* __restrict__ res,
    void* __restrict__ Cout, void* __restrict__ Cout2, int M, int N, int K) {
  __shared__ __align__(16) unsigned short As[2][128 * 32];
  __shared__ __align__(16) unsigned short Bs[2][128 * 32];
  const int t = threadIdx.x;
  const int lane = t & 63;
  const int wave = t >> 6;
  const int g = lane >> 4;
  const int lr = lane & 15;
  const int waveM = wave >> 1, waveN = wave & 1;
  const int rowBase = blockIdx.x * 128;
  const int colBase = blockIdx.y * 128;
  const int Keff = (MODE == 5) ? (K >> 1) : K;
  const int kBase = (MODE == 5) ? blockIdx.z * Keff : 0;

  f32x4 acc[4][4];
  #pragma unroll
  for (int m = 0; m < 4; ++m)
    #pragma unroll
    for (int n = 0; n < 4; ++n) acc[m][n] = (f32x4){0.f, 0.f, 0.f, 0.f};

  const int c0 = t, c1 = t + 256;
  const int r0s = c0 >> 2, s0 = (c0 & 3) ^ (r0s & 3);
  const int r1s = c1 >> 2, s1 = (c1 & 3) ^ (r1s & 3);
  const unsigned short* gA0 = A + (size_t)(rowBase + r0s) * K + kBase + s0 * 8;
  const unsigned short* gA1 = A + (size_t)(rowBase + r1s) * K + kBase + s1 * 8;
  const unsigned short* gB0 = B + (size_t)(colBase + r0s) * K + kBase + s0 * 8;
  const unsigned short* gB1 = B + (size_t)(colBase + r1s) * K + kBase + s1 * 8;

  // prologue: stage tile 0 into buf 0
  load_lds16(gA0, &As[0][wave * 512]);
  load_lds16(gA1, &As[0][2048 + wave * 512]);
  load_lds16(gB0, &Bs[0][wave * 512]);
  load_lds16(gB1, &Bs[0][2048 + wave * 512]);
  __syncthreads();

  const int nk = Keff >> 5;
  for (int kt = 0; kt < nk; ++kt) {
    const int buf = kt & 1;
    if (kt + 1 < nk) {  // prefetch next tile into other buffer
      const int k0 = (kt + 1) << 5;
      load_lds16(gA0 + k0, &As[buf ^ 1][wave * 512]);
      load_lds16(gA1 + k0, &As[buf ^ 1][2048 + wave * 512]);
      load_lds16(gB0 + k0, &Bs[buf ^ 1][wave * 512]);
      load_lds16(gB1 + k0, &Bs[buf ^ 1][2048 + wave * 512]);
    }
    bf16x8 af[4], bfr[4];
    #pragma unroll
    for (int m = 0; m < 4; ++m) {
      const int r = waveM * 64 + m * 16 + lr;
      af[m] = *(const bf16x8*)&As[buf][r * 32 + ((g ^ (r & 3)) << 3)];
    }
    #pragma unroll
    for (int n = 0; n < 4; ++n) {
      const int c = waveN * 64 + n * 16 + lr;
      bfr[n] = *(const bf16x8*)&Bs[buf][c * 32 + ((g ^ (c & 3)) << 3)];
    }
    #pragma unroll
    for (int m = 0; m < 4; ++m)
      #pragma unroll
      for (int n = 0; n < 4; ++n)
        acc[m][n] = __builtin_amdgcn_mfma_f32_16x16x32_bf16(af[m], bfr[n],
                                                            acc[m][n], 0, 0, 0);
    __syncthreads();  // drains vmcnt(0): prefetched buf ready; reads done
  }

  const int crow0 = rowBase + waveM * 64;
  const int ccol0 = colBase + waveN * 64;
  #pragma unroll
  for (int n = 0; n < 4; ++n) {
    const int col = ccol0 + n * 16 + lr;
    const float bv = bias[col];
    #pragma unroll
    for (int m = 0; m < 4; ++m) {
      const int row0 = crow0 + m * 16 + g * 4;
      if (MODE == 4) {
        if (col < 2048) {
          #pragma unroll
          for (int j = 0; j < 4; ++j)
            ((unsigned short*)Cout)[(size_t)(row0 + j) * 2048 + col] =
                f2bf(acc[m][n][j] + bv);
        } else {
          ushort4 o4;
          o4.x = f2bf(acc[m][n][0] + bv);
          o4.y = f2bf(acc[m][n][1] + bv);
          o4.z = f2bf(acc[m][n][2] + bv);
          o4.w = f2bf(acc[m][n][3] + bv);
          *(ushort4*)&((unsigned short*)Cout2)[(size_t)(col - 2048) * M + row0] = o4;
        }
      } else if (MODE == 1) {
        #pragma unroll
        for (int j = 0; j < 4; ++j)
          ((unsigned short*)Cout)[(size_t)(row0 + j) * N + col] =
              f2bf(fmaxf(acc[m][n][j] + bv, 0.f));
      } else if (MODE == 5) {
        if (blockIdx.z == 0) {
          #pragma unroll
          for (int j = 0; j < 4; ++j)
            ((float*)Cout)[(size_t)(row0 + j) * N + col] = acc[m][n][j] + bv;
        } else {
          #pragma unroll
          for (int j = 0; j < 4; ++j)
            ((float*)Cout2)[(size_t)(row0 + j) * N + col] = acc[m][n][j];
        }
      } else {
        #pragma unroll
        for (int j = 0; j < 4; ++j)
          ((float*)Cout)[(size_t)(row0 + j) * N + col] =
              acc[m][n][j] + bv + res[(size_t)(row0 + j) * N + col];
      }
    }
  }
}

// ---------------- flash attention, swapped-QK 32x32 structure ----------------
// grid: 512 blocks (xcd-swizzled over (head, qtile)); 256 threads = 4 waves,
// each wave owns 32 q-rows. KVBLK=64, double-buffered K/V LDS.
// Softmax in log2 domain with shifted accumulator init (C = -mreg).
__global__ __launch_bounds__(256, 2) void attn_kernel(
    const unsigned short* __restrict__ QK,  // [SQ][2048]: Q cols 0-1023, K 1024-2047
    const unsigned short* __restrict__ Vt,  // [HID][SQ]  (per-head transposed)
    unsigned short* __restrict__ ctx) {     // [SQ][HID]
  const int s = blockIdx.y * gridDim.x + blockIdx.x;  // 0..511
  const int q6 = s >> 3;                              // 0..63
  const int h = (s & 7) * 2 + (q6 >> 5);
  const int qt = q6 & 31;

  const int t = threadIdx.x;
  const int lane = t & 63;
  const int wave = t >> 6;
  const int ql = lane & 31;
  const int hi = lane >> 5;

  __shared__ __align__(16) unsigned short Ks[2][64 * 64];
  __shared__ __align__(16) unsigned short Vs[2][64 * 64];

  // Q fragments: lane holds Q[q = qbase+ql][d = ks*16 + hi*8 + 0..7]
  const int qbase = qt * 128 + wave * 32;
  const unsigned short* qptr =
      QK + (size_t)(qbase + ql) * 2048 + h * DH + hi * 8;
  bf16x8 qf[4];
  #pragma unroll
  for (int ks = 0; ks < 4; ++ks) qf[ks] = *(const bf16x8*)(qptr + ks * 16);

  // staging source pointers (pre-swizzled global, linear LDS dest)
  const int cr = t >> 3, cs = t & 7;
  const int cr2 = cr + 32;
  const unsigned short* gK0 =
      QK + (size_t)cr * 2048 + 1024 + h * DH + ((cs ^ (cr & 7)) << 3);
  const unsigned short* gK1 =
      QK + (size_t)cr2 * 2048 + 1024 + h * DH + ((cs ^ (cr2 & 7)) << 3);
  const unsigned short* gV0 = Vt + (size_t)(h * DH + cr) * SQ + ((cs ^ (cr & 7)) << 3);
  const unsigned short* gV1 = Vt + (size_t)(h * DH + cr2) * SQ + ((cs ^ (cr2 & 7)) << 3);

  float mreg = 0.f, lreg = 0.f;
  f32x16 oacc0 = 0.f, oacc1 = 0.f;

  // prologue: stage tile 0 into buf 0
  load_lds16(gK0, &Ks[0][wave * 512]);
  load_lds16(gK1, &Ks[0][2048 + wave * 512]);
  load_lds16(gV0, &Vs[0][wave * 512]);
  load_lds16(gV1, &Vs[0][2048 + wave * 512]);

  for (int kt = 0; kt < SQ / 64; ++kt) {
    const int buf = kt & 1;
    __syncthreads();  // staged buf ready (vmcnt drain), prev compute done
    if (kt + 1 < SQ / 64) {
      const size_t ko = (size_t)(kt + 1) * 64 * 2048;
      const int vo = (kt + 1) * 64;
      load_lds16(gK0 + ko, &Ks[buf ^ 1][wave * 512]);
      load_lds16(gK1 + ko, &Ks[buf ^ 1][2048 + wave * 512]);
      load_lds16(gV0 + vo, &Vs[buf ^ 1][wave * 512]);
      load_lds16(gV1 + vo, &Vs[buf ^ 1][2048 + wave * 512]);
    }
    const unsigned short* KsB = &Ks[buf][0];
    const unsigned short* VsB = &Vs[buf][0];

    // swapped QK^T with shifted C-init: st = S - mreg directly
    f32x16 st0, st1;
    #pragma unroll
    for (int r = 0; r < 16; ++r) { st0[r] = -mreg; st1[r] = -mreg; }
    __builtin_amdgcn_s_setprio(1);
    #pragma unroll
    for (int ks = 0; ks < 4; ++ks) {
      const int sl = ((((ks << 1) | hi) ^ (ql & 7)) << 3);
      const bf16x8 k0 = *(const bf16x8*)&KsB[ql * 64 + sl];
      const bf16x8 k1 = *(const bf16x8*)&KsB[(32 + ql) * 64 + sl];
      st0 = __builtin_amdgcn_mfma_f32_32x32x16_bf16(k0, qf[ks], st0, 0, 0, 0);
      st1 = __builtin_amdgcn_mfma_f32_32x32x16_bf16(k1, qf[ks], st1, 0, 0, 0);
    }
    __builtin_amdgcn_s_setprio(0);

    // V frags (issue early; consumed after softmax)
    bf16x8 vf0[4], vf1[4];
    #pragma unroll
    for (int ks = 0; ks < 4; ++ks) {
      const int sl = ((((ks << 1) | hi) ^ (ql & 7)) << 3);
      vf0[ks] = *(const bf16x8*)&VsB[ql * 64 + sl];
      vf1[ks] = *(const bf16x8*)&VsB[(32 + ql) * 64 + sl];
    }

    // ---- online softmax (log2 domain, values pre-shifted by -mreg) ----
    float tr[16];
    #pragma unroll
    for (int r = 0; r < 16; ++r) tr[r] = fmaxf(st0[r], st1[r]);
    #pragma unroll
    for (int s2 = 8; s2 > 0; s2 >>= 1)
      #pragma unroll
      for (int r = 0; r < s2; ++r) tr[r] = fmaxf(tr[r], tr[r + s2]);
    const float mx = fmaxf(tr[0], __shfl_xor(tr[0], 32));

    if (!__all(mx <= 8.0f)) {  // defer-max rescale (T13)
      const float mpos = fmaxf(mx, 0.f);
      const float corr = fexp2(-mpos);
      mreg += mpos;
      lreg *= corr;
      #pragma unroll
      for (int r = 0; r < 16; ++r) { st0[r] -= mpos; st1[r] -= mpos; }
      #pragma unroll
      for (int r = 0; r < 16; ++r) {
        const float c = __shfl(corr, (r & 3) + 8 * (r >> 2) + 4 * hi);
        oacc0[r] *= c;
        oacc1[r] *= c;
      }
    }

    #pragma unroll
    for (int r = 0; r < 16; ++r) st0[r] = fexp2(st0[r]);
    #pragma unroll
    for (int r = 0; r < 16; ++r) st1[r] = fexp2(st1[r]);
    float ts[16];
    #pragma unroll
    for (int r = 0; r < 16; ++r) ts[r] = st0[r] + st1[r];
    #pragma unroll
    for (int s2 = 8; s2 > 0; s2 >>= 1)
      #pragma unroll
      for (int r = 0; r < s2; ++r) ts[r] += ts[r + s2];
    lreg += ts[0] + __shfl_xor(ts[0], 32);

    // ---- P -> A-frag via cvt_pk + permlane32_swap (T12) ----
    union { int w[4]; bf16x8 v; } pa[4];
    #pragma unroll
    for (int half = 0; half < 2; ++half) {
      #pragma unroll
      for (int kk = 0; kk < 2; ++kk) {
        const int base = kk * 8;
        float p0, p1, p2, p3, p4, p5, p6, p7;
        if (half == 0) {
          p0 = st0[base + 0]; p1 = st0[base + 1]; p2 = st0[base + 2]; p3 = st0[base + 3];
          p4 = st0[base + 4]; p5 = st0[base + 5]; p6 = st0[base + 6]; p7 = st0[base + 7];
        } else {
          p0 = st1[base + 0]; p1 = st1[base + 1]; p2 = st1[base + 2]; p3 = st1[base + 3];
          p4 = st1[base + 4]; p5 = st1[base + 5]; p6 = st1[base + 6]; p7 = st1[base + 7];
        }
        const int d0 = cvtpk_bf16(p0, p1), sw0 = cvtpk_bf16(p4, p5);
        const int d1 = cvtpk_bf16(p2, p3), sw1 = cvtpk_bf16(p6, p7);
        auto a = __builtin_amdgcn_permlane32_swap(d0, sw0, false, false);
        auto b = __builtin_amdgcn_permlane32_swap(d1, sw1, false, false);
        const int ks = half * 2 + kk;
        pa[ks].w[0] = a[0]; pa[ks].w[1] = b[0];
        pa[ks].w[2] = a[1]; pa[ks].w[3] = b[1];
      }
    }

    // ---- PV ----
    __builtin_amdgcn_s_setprio(1);
    #pragma unroll
    for (int ks = 0; ks < 4; ++ks) {
      oacc0 = __builtin_amdgcn_mfma_f32_32x32x16_bf16(pa[ks].v, vf0[ks], oacc0, 0, 0, 0);
      oacc1 = __builtin_amdgcn_mfma_f32_32x32x16_bf16(pa[ks].v, vf1[ks], oacc1, 0, 0, 0);
    }
    __builtin_amdgcn_s_setprio(0);
  }

  // ---- epilogue: divide by l, write ctx ----
  const float linv = 1.0f / lreg;
  #pragma unroll
  for (int r = 0; r < 16; ++r) {
    const int qq = (r & 3) + 8 * (r >> 2) + 4 * hi;
    const float li = __shfl(linv, qq);
    unsigned short* cp = ctx + (size_t)(qbase + qq) * HID + h * DH + ql;
    cp[0] = f2bf(oacc0[r] * li);
    cp[32] = f2bf(oacc1[r] * li);
  }
}

extern "C" void kernel_launch(void* const* d_in, const int* in_sizes, int n_in,
                              void* d_out, int out_size, void* d_ws,
                              size_t ws_size, hipStream_t stream) {
  const float* x     = (const float*)d_in[0];
  const float* an_w  = (const float*)d_in[1];
  const float* an_b  = (const float*)d_in[2];
  const float* q_w   = (const float*)d_in[3];
  const float* q_b   = (const float*)d_in[4];
  const float* k_w   = (const float*)d_in[5];
  const float* k_b   = (const float*)d_in[6];
  const float* v_w   = (const float*)d_in[7];
  const float* v_b   = (const float*)d_in[8];
  const float* o_w   = (const float*)d_in[9];
  const float* o_b   = (const float*)d_in[10];
  const float* fn_w  = (const float*)d_in[11];
  const float* fn_b  = (const float*)d_in[12];
  const float* ff1_w = (const float*)d_in[13];
  const float* ff1_b = (const float*)d_in[14];
  const float* ff2_w = (const float*)d_in[15];
  const float* ff2_b = (const float*)d_in[16];

  char* ws = (char*)d_ws;
  const size_t MB = 1ull << 20;
  unsigned short* xn    = (unsigned short*)(ws + 0);       // 8MB, reused as x2n
  unsigned short* qkvwb = (unsigned short*)(ws + 8 * MB);  // 6MB [3072][1024]
  unsigned short* owb   = (unsigned short*)(ws + 14 * MB); // 2MB
  unsigned short* f1wb  = (unsigned short*)(ws + 16 * MB); // 8MB
  unsigned short* f2wb  = (unsigned short*)(ws + 24 * MB); // 8MB
  unsigned short* QKm   = (unsigned short*)(ws + 32 * MB); // 16MB [SQ][2048]
  unsigned short* Vtm   = (unsigned short*)(ws + 48 * MB); // 8MB [1024][SQ]
  unsigned short* ctx   = (unsigned short*)(ws + 56 * MB); // 8MB
  float*          bAll  = (float*)(ws + 56 * MB);          // 12KB (dead before ctx written)
  float*          x2    = (float*)(ws + 64 * MB);          // 16MB fp32
  unsigned short* hbuf  = (unsigned short*)(ws + 32 * MB); // 32MB reuse QK/Vt/ctx
  unsigned short* x2n   = xn;
  float*          p1    = (float*)(ws + 0);                // 16MB (xn+weights dead by FF2)

  // weight conversion (q region pre-scaled) + bias concat
  cvt6_kernel<<<12288, 256, 0, stream>>>(q_w, k_w, v_w, o_w, ff1_w, ff2_w, qkvwb);
  bias3_kernel<<<3, 256, 0, stream>>>(q_b, k_b, v_b, bAll);

  // LN1
  ln_kernel<<<SQ, 256, 0, stream>>>(x, an_w, an_b, xn);

  // fused QKV projection: N=3072, writes QKm (Q,K) + Vtm (V transposed)
  gemm_bt<4><<<dim3(SQ / 128, 3072 / 128), 256, 0, stream>>>(
      xn, qkvwb, bAll, nullptr, QKm, Vtm, SQ, 3072, HID);

  // attention
  attn_kernel<<<dim3(32, 16), 256, 0, stream>>>(QKm, Vtm, ctx);

  // O projection + residual -> x2 (fp32)
  gemm_bt<2><<<dim3(SQ / 128, HID / 128), 256, 0, stream>>>(
      ctx, owb, o_b, x, x2, nullptr, SQ, HID, HID);

  // LN2
  ln_kernel<<<SQ, 256, 0, stream>>>(x2, fn_w, fn_b, x2n);

  // FF1 + relu -> h (bf16)
  gemm_bt<1><<<dim3(SQ / 128, INTER_DIM / 128), 256, 0, stream>>>(
      x2n, f1wb, ff1_b, nullptr, hbuf, nullptr, SQ, INTER_DIM, HID);

  // FF2 split-K: z=0 -> d_out = acc+bias, z=1 -> p1 = acc
  gemm_bt<5><<<dim3(SQ / 128, HID / 128, 2), 256, 0, stream>>>(
      hbuf, f2wb, ff2_b, nullptr, (float*)d_out, p1, SQ, HID, INTER_DIM);

  // out += p1 + x2 (residual)
  combine_kernel<<<(SQ * HID) / 1024, 256, 0, stream>>>((float*)d_out, p1, x2);
}